// Round 1
// baseline (186.117 us; speedup 1.0000x reference)
//
#include <hip/hip_runtime.h>

// B=8, N=256, M=16, D=256; loss = sum logsumexp_k(S) - sum S_self
constexpr int B = 8, N = 256, M = 16, D = 256;
constexpr int DC = D / 4; // 64 float4 chunks along D

__device__ __forceinline__ float waveSum(float v) {
#pragma unroll
  for (int off = 32; off > 0; off >>= 1) v += __shfl_down(v, off, 64);
  return v;
}
__device__ __forceinline__ float waveMax(float v) {
#pragma unroll
  for (int off = 32; off > 0; off >>= 1) v = fmaxf(v, __shfl_down(v, off, 64));
  return v;
}

// Kernel 1: centroids, stored transposed+packed: cq[(b*DC+dc)*N + k] = {c[b][k][4dc+q]}_{q=0..3}
__global__ __launch_bounds__(256) void k_centroid(const float* __restrict__ e,
                                                  float4* __restrict__ cq,
                                                  float* __restrict__ out) {
  const int blk = blockIdx.x;          // blk = b*N + k
  const int t = threadIdx.x;           // t = d
  const int b = blk >> 8, k = blk & 255;
  const float* ek = e + (size_t)blk * (M * D); // [M][D]
  float s = 0.f;
#pragma unroll
  for (int i = 0; i < M; ++i) s += ek[i * D + t];
  __shared__ float cl[D];
  cl[t] = s * (1.f / M);
  __syncthreads();
  if (t < DC) {
    float4 v = make_float4(cl[4 * t + 0], cl[4 * t + 1], cl[4 * t + 2], cl[4 * t + 3]);
    cq[(size_t)(b * DC + t) * N + k] = v;
  }
  if (blk == 0 && t == 0) out[0] = 0.f; // d_out is re-poisoned 0xAA before every launch
}

// Kernel 2: one block per (b,j); thread t = centroid index k.
__global__ __launch_bounds__(256) void k_main(const float* __restrict__ e,
                                              const float4* __restrict__ cq,
                                              const float* __restrict__ wp,
                                              const float* __restrict__ bp,
                                              float* __restrict__ out) {
  const int blk = blockIdx.x;          // blk = b*N + j
  const int t = threadIdx.x;           // t = k
  const int b = blk >> 8, j = blk & 255;
  const int lane = t & 63, wv = t >> 6;
  const float w = *wp, bb = *bp;
  const float* eblk = e + (size_t)blk * (M * D);     // e[b][j][i][d], block-uniform base
  const float4* cb = cq + (size_t)b * DC * N;

  float acc[M];
#pragma unroll
  for (int i = 0; i < M; ++i) acc[i] = 0.f;

  // Main GEMM loop: acc[i] = dot(e[b][j][i][:], c[b][t][:])
  for (int dc = 0; dc < DC; ++dc) {
    float4 cv = cb[dc * N + t];        // coalesced float4 per thread
#pragma unroll
    for (int i = 0; i < M; ++i) {
      // block-uniform addresses -> scalar loads (SGPR operands for the FMAs)
      float e0 = eblk[i * D + 4 * dc + 0];
      float e1 = eblk[i * D + 4 * dc + 1];
      float e2 = eblk[i * D + 4 * dc + 2];
      float e3 = eblk[i * D + 4 * dc + 3];
      acc[i] = fmaf(e3, cv.w, fmaf(e2, cv.z, fmaf(e1, cv.y, fmaf(e0, cv.x, acc[i]))));
    }
  }

  __shared__ float red[M][4];
  __shared__ float red2[M][4];
  __shared__ float down[M];

  // sqnorm[i] = sum_d e[i][d]^2 : distributed over threads (d = t), wave+block reduce
#pragma unroll
  for (int i = 0; i < M; ++i) {
    float ei = eblk[i * D + t];
    float p = waveSum(ei * ei);
    if (lane == 0) red[i][wv] = p;
  }
  if (t == j) { // this thread holds dot_own[i] = dot(e_bji, c_bj)
#pragma unroll
    for (int i = 0; i < M; ++i) down[i] = acc[i];
  }
  __syncthreads();

  float sself_sum = 0.f;
#pragma unroll
  for (int i = 0; i < M; ++i) {
    float sq = red[i][0] + red[i][1] + red[i][2] + red[i][3];
    float sself = fmaf(w, (M * down[i] - sq) * (1.f / (M - 1)), bb);
    sself_sum += sself;
    float s = (t == j) ? sself : fmaf(w, acc[i], bb);
    acc[i] = s;                        // reuse acc to hold S[i][t]
    float m = waveMax(s);
    if (lane == 0) red2[i][wv] = m;
  }
  __syncthreads();

#pragma unroll
  for (int i = 0; i < M; ++i) {
    float m = fmaxf(fmaxf(red2[i][0], red2[i][1]), fmaxf(red2[i][2], red2[i][3]));
    float ex = __expf(acc[i] - m);
    float p = waveSum(ex);
    if (lane == 0) red[i][wv] = p;     // red[i] reads all completed before prior barrier
    acc[i] = m;                        // keep row max
  }
  __syncthreads();

  float lossp = 0.f;
#pragma unroll
  for (int i = 0; i < M; ++i) {
    float sum = red[i][0] + red[i][1] + red[i][2] + red[i][3];
    lossp += acc[i] + __logf(sum);     // logsumexp
  }
  lossp -= sself_sum;
  if (t == 0) atomicAdd(out, lossp);
}

extern "C" void kernel_launch(void* const* d_in, const int* in_sizes, int n_in,
                              void* d_out, int out_size, void* d_ws, size_t ws_size,
                              hipStream_t stream) {
  const float* e = (const float*)d_in[0];   // [B,N,M,D] fp32
  const float* wp = (const float*)d_in[1];  // scalar w
  const float* bp = (const float*)d_in[2];  // scalar b
  float* out = (float*)d_out;               // 1 float
  float4* cq = (float4*)d_ws;               // B*DC*N float4 = 2 MB scratch

  k_centroid<<<B * N, 256, 0, stream>>>(e, cq, out);
  k_main<<<B * N, 256, 0, stream>>>(e, cq, wp, bp, out);
}

// Round 2
// 130.154 us; speedup vs baseline: 1.4300x; 1.4300x over previous
//
#include <hip/hip_runtime.h>

// B=8, N=256, M=16, D=256
// loss = sum_rows logsumexp_k(S) - sum S_self,  S = w*<e,c_k>+b with LOO diagonal
constexpr int B = 8, N = 256, M = 16, D = 256;

typedef short bf16x8 __attribute__((ext_vector_type(8)));
typedef float f32x4 __attribute__((ext_vector_type(4)));

__device__ __forceinline__ unsigned short f2bf(float x) {
  unsigned u = __float_as_uint(x);
  u = (u + 0x7FFFu + ((u >> 16) & 1u)) >> 16;   // RNE
  return (unsigned short)u;
}
__device__ __forceinline__ uint4 pack8(const unsigned short* s) {
  uint4 u;
  u.x = (unsigned)s[0] | ((unsigned)s[1] << 16);
  u.y = (unsigned)s[2] | ((unsigned)s[3] << 16);
  u.z = (unsigned)s[4] | ((unsigned)s[5] << 16);
  u.w = (unsigned)s[6] | ((unsigned)s[7] << 16);
  return u;
}

// ws layout:
//  EbfA [0,16MB):        uint4[(b*256+j)*8+kc][lane]  A-frag swizzled bf16 E
//    frag: lane l holds A[m=l&15][k=kc*32+(l>>4)*8 + 0..7]
//  Cbf  [16MB,17MB):     uint4[(b*8+kc)*16+nt][lane]  B-frag swizzled bf16 centroids
//    frag: lane l holds C[n=nt*16+(l&15)][k=kc*32+(l>>4)*8 + 0..7]
//  SQ   [17MB,+128KB):   float[b*4096+row]  (fp32 ||e||^2 per row)

__global__ __launch_bounds__(256) void k_prep(const float* __restrict__ e,
                                              uint4* __restrict__ EbfA,
                                              uint4* __restrict__ Cbf,
                                              float* __restrict__ SQ,
                                              float* __restrict__ out) {
  const int blk = blockIdx.x;            // b*256 + j
  const int t = threadIdx.x;
  const int b = blk >> 8, j = blk & 255;
  const float* ek = e + (size_t)blk * (M * D);   // [16][256]
  __shared__ float cl[D];
  __shared__ float lt[M * 260];                  // padded fp32 tile

  float ev[M];
  float cs = 0.f;
#pragma unroll
  for (int i = 0; i < M; ++i) { ev[i] = ek[i * D + t]; cs += ev[i]; }
  cl[t] = cs * (1.f / M);
#pragma unroll
  for (int i = 0; i < M; ++i) lt[i * 260 + t] = ev[i];
  __syncthreads();

  // sqnorm (fp32): row r = t>>4, 16-elem segment sg = t&15; quad shuffle-reduce
  {
    const int r = t >> 4, sg = t & 15;
    const float* row = &lt[r * 260 + sg * 16];
    float p = 0.f;
#pragma unroll
    for (int x = 0; x < 16; ++x) p += row[x] * row[x];
#pragma unroll
    for (int mk = 1; mk < 16; mk <<= 1) p += __shfl_xor(p, mk, 64);
    if (sg == 0) SQ[blk * 16 + r] = p;
  }

  // centroid j -> B-frag slots (threads 0..31 handle 8 dims each)
  if (t < 32) {
    const int kc = t >> 2, q = t & 3;
    unsigned short s[8];
#pragma unroll
    for (int x = 0; x < 8; ++x) s[x] = f2bf(cl[kc * 32 + q * 8 + x]);
    Cbf[(size_t)((b * 8 + kc) * 16 + (j >> 4)) * 64 + (q * 16 + (j & 15))] = pack8(s);
  }

  // E tile -> A-frag slots: lane l of chunk kc holds rows m=l&15, k run of 8
  {
    const int l = t & 63, g = t >> 6;
    const int m = l & 15, q = l >> 4;
#pragma unroll
    for (int kk = 0; kk < 2; ++kk) {
      const int kc = g + kk * 4;
      const float* src = &lt[m * 260 + kc * 32 + q * 8];
      unsigned short s[8];
#pragma unroll
      for (int x = 0; x < 8; ++x) s[x] = f2bf(src[x]);
      EbfA[(size_t)(blk * 8 + kc) * 64 + l] = pack8(s);   // coalesced 16B/lane
    }
  }
  if (blk == 0 && t == 0) out[0] = 0.f;  // d_out re-poisoned each launch
}

// One block per (b, 128-row strip). 4 waves in 2x2: h=rows half, c=cols half.
// Wave: 4 row-tiles x 8 col-tiles of 16x16x32 MFMA, acc 128 VGPRs. No LDS in K-loop.
__global__ __launch_bounds__(256, 1) void k_gemm(const uint4* __restrict__ EbfA,
                                                 const uint4* __restrict__ Cbf,
                                                 const float* __restrict__ SQ,
                                                 const float* __restrict__ wp,
                                                 const float* __restrict__ bp,
                                                 float* __restrict__ out) {
  const int blk = blockIdx.x;               // b*32 + strip
  const int b = blk >> 5, strip = blk & 31;
  const int tid = threadIdx.x;
  const int wid = tid >> 6, lane = tid & 63;
  const int h = wid >> 1, c = wid & 1;      // row-half, col-half
  const int q = lane >> 4, cl_ = lane & 15;

  const uint4* Ab = EbfA + (size_t)((b * 256 + strip * 8 + h * 4) * 8) * 64 + lane;
  const uint4* Bb = Cbf + (size_t)(b * 128 + c * 8) * 64 + lane;

  f32x4 acc[4][8];
#pragma unroll
  for (int rt = 0; rt < 4; ++rt)
#pragma unroll
    for (int nt = 0; nt < 8; ++nt) acc[rt][nt] = (f32x4)0.f;

  uint4 a_cur[4], b_cur[8];
#pragma unroll
  for (int rt = 0; rt < 4; ++rt) a_cur[rt] = Ab[rt * 8 * 64];
#pragma unroll
  for (int nt = 0; nt < 8; ++nt) b_cur[nt] = Bb[nt * 64];

#pragma unroll
  for (int kc = 0; kc < 8; ++kc) {
    uint4 a_nxt[4], b_nxt[8];
    if (kc < 7) {
#pragma unroll
      for (int rt = 0; rt < 4; ++rt) a_nxt[rt] = Ab[(rt * 8 + kc + 1) * 64];
#pragma unroll
      for (int nt = 0; nt < 8; ++nt) b_nxt[nt] = Bb[((kc + 1) * 16 + nt) * 64];
    }
#pragma unroll
    for (int rt = 0; rt < 4; ++rt) {
      bf16x8 av = __builtin_bit_cast(bf16x8, a_cur[rt]);
#pragma unroll
      for (int nt = 0; nt < 8; ++nt) {
        acc[rt][nt] = __builtin_amdgcn_mfma_f32_16x16x32_bf16(
            av, __builtin_bit_cast(bf16x8, b_cur[nt]), acc[rt][nt], 0, 0, 0);
      }
    }
    if (kc < 7) {
#pragma unroll
      for (int rt = 0; rt < 4; ++rt) a_cur[rt] = a_nxt[rt];
#pragma unroll
      for (int nt = 0; nt < 8; ++nt) b_cur[nt] = b_nxt[nt];
    }
  }

  // ---- epilogue ----
  const float w = *wp, bias = *bp;
  __shared__ float lmx[2][128];
  __shared__ float lsm[2][128];
  __shared__ float bred[4];

  float ssum = 0.f;
  float mfull[4][4];   // [rt][reg]

  // scale + diagonal LOO replace + per-half row max
#pragma unroll
  for (int rt = 0; rt < 4; ++rt) {
    const int jR = strip * 8 + h * 4 + rt;          // diag col for this row-tile
    const bool own = ((jR >> 7) == c) && (cl_ == (jR & 15));
    const int ntd = (jR >> 4) & 7;
    float rawd[4];
    if (own) {
#pragma unroll
      for (int reg = 0; reg < 4; ++reg) rawd[reg] = acc[rt][ntd][reg];
    }
#pragma unroll
    for (int nt = 0; nt < 8; ++nt)
#pragma unroll
      for (int reg = 0; reg < 4; ++reg) acc[rt][nt][reg] = w * acc[rt][nt][reg] + bias;
    if (own) {
#pragma unroll
      for (int reg = 0; reg < 4; ++reg) {
        const int Rl = h * 64 + rt * 16 + q * 4 + reg;
        const float sq = SQ[b * 4096 + strip * 128 + Rl];
        const float sself = w * (16.f * rawd[reg] - sq) * (1.f / 15.f) + bias;
        acc[rt][ntd][reg] = sself;
        ssum += sself;
      }
    }
#pragma unroll
    for (int reg = 0; reg < 4; ++reg) {
      float mx = -3.4e38f;
#pragma unroll
      for (int nt = 0; nt < 8; ++nt) mx = fmaxf(mx, acc[rt][nt][reg]);
#pragma unroll
      for (int mk = 1; mk < 16; mk <<= 1) mx = fmaxf(mx, __shfl_xor(mx, mk, 64));
      mfull[rt][reg] = mx;
      if (cl_ == 0) lmx[c][h * 64 + rt * 16 + q * 4 + reg] = mx;
    }
  }
  __syncthreads();

  // combine halves' maxes; sum exp
#pragma unroll
  for (int rt = 0; rt < 4; ++rt) {
#pragma unroll
    for (int reg = 0; reg < 4; ++reg) {
      const int Rl = h * 64 + rt * 16 + q * 4 + reg;
      const float mx = fmaxf(lmx[0][Rl], lmx[1][Rl]);
      mfull[rt][reg] = mx;
      float se = 0.f;
#pragma unroll
      for (int nt = 0; nt < 8; ++nt) se += expf(acc[rt][nt][reg] - mx);
#pragma unroll
      for (int mk = 1; mk < 16; mk <<= 1) se += __shfl_xor(se, mk, 64);
      if (cl_ == 0) lsm[c][Rl] = se;
    }
  }
  __syncthreads();

  float part = -ssum;
  if (c == 0 && cl_ == 0) {
#pragma unroll
    for (int rt = 0; rt < 4; ++rt)
#pragma unroll
      for (int reg = 0; reg < 4; ++reg) {
        const int Rl = h * 64 + rt * 16 + q * 4 + reg;
        part += mfull[rt][reg] + logf(lsm[0][Rl] + lsm[1][Rl]);
      }
  }
#pragma unroll
  for (int mk = 1; mk < 64; mk <<= 1) part += __shfl_xor(part, mk, 64);
  if (lane == 0) bred[wid] = part;
  __syncthreads();
  if (tid == 0) atomicAdd(out, bred[0] + bred[1] + bred[2] + bred[3]);
}

extern "C" void kernel_launch(void* const* d_in, const int* in_sizes, int n_in,
                              void* d_out, int out_size, void* d_ws, size_t ws_size,
                              hipStream_t stream) {
  const float* e = (const float*)d_in[0];
  const float* wp = (const float*)d_in[1];
  const float* bp = (const float*)d_in[2];
  float* out = (float*)d_out;
  char* ws = (char*)d_ws;
  uint4* EbfA = (uint4*)ws;                                   // 16 MB
  uint4* Cbf = (uint4*)(ws + (size_t)16 * 1024 * 1024);       // 1 MB
  float* SQ = (float*)(ws + (size_t)17 * 1024 * 1024);        // 128 KB

  k_prep<<<B * N, 256, 0, stream>>>(e, EbfA, Cbf, SQ, out);
  k_gemm<<<B * 32, 256, 0, stream>>>(EbfA, Cbf, SQ, wp, bp, out);
}

// Round 3
// 97.018 us; speedup vs baseline: 1.9184x; 1.3415x over previous
//
#include <hip/hip_runtime.h>

// B=8, N=256, M=16, D=256
// loss = sum_rows logsumexp_k(S) - sum S_self, S = w*<e,c_k>+b, LOO diagonal
constexpr int B = 8, N = 256, M = 16, D = 256;

typedef short bf16x8 __attribute__((ext_vector_type(8)));
typedef float f32x4 __attribute__((ext_vector_type(4)));

__device__ __forceinline__ unsigned short f2bf(float x) {
  unsigned u = __float_as_uint(x);
  u = (u + 0x7FFFu + ((u >> 16) & 1u)) >> 16;  // RNE
  return (unsigned short)u;
}
__device__ __forceinline__ uint4 packbf8(const float* f) {
  uint4 u;
  u.x = (unsigned)f2bf(f[0]) | ((unsigned)f2bf(f[1]) << 16);
  u.y = (unsigned)f2bf(f[2]) | ((unsigned)f2bf(f[3]) << 16);
  u.z = (unsigned)f2bf(f[4]) | ((unsigned)f2bf(f[5]) << 16);
  u.w = (unsigned)f2bf(f[6]) | ((unsigned)f2bf(f[7]) << 16);
  return u;
}

// ws: EbfA [0,16MB) A-frags: uint4[(b*256+j)*8+kc][lane], lane l = row m=l&15,
//       dims kc*32+(l>>4)*8..+7.  Cbf [16,17MB) B-frags: uint4[(b*8+kc)*16+nt][lane],
//       lane l = col n=nt*16+(l&15), dims kc*32+(l>>4)*8..+7.  SQ [17MB,+128KB) fp32 row sqnorms.

// LDS-free prep: one block per (b,j). Lane directly loads its A-frag floats.
__global__ __launch_bounds__(256) void k_prep(const float* __restrict__ e,
                                              uint4* __restrict__ EbfA,
                                              uint4* __restrict__ Cbf,
                                              float* __restrict__ SQ,
                                              float* __restrict__ out) {
  const int blk = blockIdx.x;  // b*256 + j
  const int b = blk >> 8, j = blk & 255;
  const int t = threadIdx.x;
  const int w = t >> 6, l = t & 63;
  const int m = l & 15, q = l >> 4;
  const float* base = e + (size_t)blk * (M * D);

  float sqp = 0.f;
  __shared__ float sqred[4][16];

#pragma unroll
  for (int kk = 0; kk < 2; ++kk) {
    const int kc = w * 2 + kk;
    const float* src = base + m * D + kc * 32 + q * 8;  // 32B-aligned
    float f[8];
#pragma unroll
    for (int x = 0; x < 4; ++x) f[x] = ((const float4*)src)->x, f[x] = src[x];
#pragma unroll
    for (int x = 0; x < 8; ++x) f[x] = src[x];
    // A-fragment store (coalesced 16B/lane)
    EbfA[(size_t)(blk * 8 + kc) * 64 + l] = packbf8(f);
    // sqnorm partial (this lane: row m, 8 dims)
#pragma unroll
    for (int x = 0; x < 8; ++x) sqp = fmaf(f[x], f[x], sqp);
    // centroid: reduce over the m lane bits (0..3)
    float cv[8];
#pragma unroll
    for (int x = 0; x < 8; ++x) cv[x] = f[x];
#pragma unroll
    for (int mk = 1; mk < 16; mk <<= 1)
#pragma unroll
      for (int x = 0; x < 8; ++x) cv[x] += __shfl_xor(cv[x], mk, 64);
    if (m == (j & 15)) {  // writer lane l == q*16 + (j&15): exactly the B-frag slot lane
      float cs[8];
#pragma unroll
      for (int x = 0; x < 8; ++x) cs[x] = cv[x] * (1.f / 16.f);
      Cbf[(size_t)((b * 8 + kc) * 16 + (j >> 4)) * 64 + l] = packbf8(cs);
    }
  }
  // sqnorm: reduce over q (bits 4,5), then across waves (kc pairs) via LDS
  sqp += __shfl_xor(sqp, 16, 64);
  sqp += __shfl_xor(sqp, 32, 64);
  if (q == 0) sqred[w][m] = sqp;
  __syncthreads();
  if (t < 16) SQ[blk * 16 + t] = sqred[0][t] + sqred[1][t] + sqred[2][t] + sqred[3][t];
  if (blk == 0 && t == 0) out[0] = 0.f;  // d_out re-poisoned each launch
}

// One block per (b, 64-row strip). 4 waves 2x2: h=row-half(2 tiles), c=col-half(8 tiles).
// acc 64 VGPRs/wave; NO dynamic register indexing anywhere.
__global__ __launch_bounds__(256) void k_gemm(const uint4* __restrict__ EbfA,
                                              const uint4* __restrict__ Cbf,
                                              const float* __restrict__ SQ,
                                              const float* __restrict__ wp,
                                              const float* __restrict__ bp,
                                              float* __restrict__ out) {
  const int blk = blockIdx.x;  // b*64 + strip
  const int b = blk >> 6, strip = blk & 63;
  const int tid = threadIdx.x;
  const int wid = tid >> 6, lane = tid & 63;
  const int h = wid >> 1, c = wid & 1;
  const int q = lane >> 4, cl_ = lane & 15;

  const uint4* Ab = EbfA + (size_t)((b * 256 + strip * 4 + h * 2) * 8) * 64 + lane;
  const uint4* Bb = Cbf + (size_t)(b * 128 + c * 8) * 64 + lane;

  f32x4 acc[2][8];
#pragma unroll
  for (int rt = 0; rt < 2; ++rt)
#pragma unroll
    for (int nt = 0; nt < 8; ++nt) acc[rt][nt] = (f32x4)0.f;

#pragma unroll 1
  for (int kc = 0; kc < 8; ++kc) {
    uint4 af0 = Ab[kc * 64];
    uint4 af1 = Ab[(8 + kc) * 64];
    uint4 bfr[8];
#pragma unroll
    for (int nt = 0; nt < 8; ++nt) bfr[nt] = Bb[(kc * 16 + nt) * 64];
    bf16x8 a0 = __builtin_bit_cast(bf16x8, af0);
    bf16x8 a1 = __builtin_bit_cast(bf16x8, af1);
#pragma unroll
    for (int nt = 0; nt < 8; ++nt) {
      bf16x8 bv = __builtin_bit_cast(bf16x8, bfr[nt]);
      acc[0][nt] = __builtin_amdgcn_mfma_f32_16x16x32_bf16(a0, bv, acc[0][nt], 0, 0, 0);
      acc[1][nt] = __builtin_amdgcn_mfma_f32_16x16x32_bf16(a1, bv, acc[1][nt], 0, 0, 0);
    }
  }

  // ---- epilogue: scale, LOO diagonal, logsumexp ----
  const float w = *wp, bias = *bp;
  __shared__ float lmx[2][64];
  __shared__ float lsm[2][64];
  __shared__ float bred[4];
  float ssum = 0.f;

#pragma unroll
  for (int rt = 0; rt < 2; ++rt) {
    const int jr = strip * 4 + h * 2 + rt;          // global row-tile == diag col
    const bool own = (c == (jr >> 7)) && (cl_ == (jr & 15));
    const int ntd = (jr >> 4) & 7;
    float sq[4];
    if (own) {
#pragma unroll
      for (int reg = 0; reg < 4; ++reg)
        sq[reg] = SQ[b * 4096 + strip * 64 + (h * 2 + rt) * 16 + q * 4 + reg];
    }
#pragma unroll
    for (int nt = 0; nt < 8; ++nt)
#pragma unroll
      for (int reg = 0; reg < 4; ++reg) {
        const float raw = acc[rt][nt][reg];
        float sv = fmaf(w, raw, bias);
        if (own && nt == ntd) {                      // predicated select, no indexing
          sv = fmaf(w * (1.f / 15.f), 16.f * raw - sq[reg], bias);
          ssum += sv;
        }
        acc[rt][nt][reg] = sv;
      }
#pragma unroll
    for (int reg = 0; reg < 4; ++reg) {
      float mx = acc[rt][0][reg];
#pragma unroll
      for (int nt = 1; nt < 8; ++nt) mx = fmaxf(mx, acc[rt][nt][reg]);
#pragma unroll
      for (int mk = 1; mk < 16; mk <<= 1) mx = fmaxf(mx, __shfl_xor(mx, mk, 64));
      if (cl_ == 0) lmx[c][(h * 2 + rt) * 16 + q * 4 + reg] = mx;
    }
  }
  __syncthreads();

#pragma unroll
  for (int rt = 0; rt < 2; ++rt)
#pragma unroll
    for (int reg = 0; reg < 4; ++reg) {
      const int Rl = (h * 2 + rt) * 16 + q * 4 + reg;
      const float mx = fmaxf(lmx[0][Rl], lmx[1][Rl]);
      float se = 0.f;
#pragma unroll
      for (int nt = 0; nt < 8; ++nt) se += __expf(acc[rt][nt][reg] - mx);
#pragma unroll
      for (int mk = 1; mk < 16; mk <<= 1) se += __shfl_xor(se, mk, 64);
      if (cl_ == 0) lsm[c][Rl] = se;
    }
  __syncthreads();

  float part = -ssum;
  if (c == 0 && cl_ == 0) {
#pragma unroll
    for (int rt = 0; rt < 2; ++rt)
#pragma unroll
      for (int reg = 0; reg < 4; ++reg) {
        const int Rl = (h * 2 + rt) * 16 + q * 4 + reg;
        const float mx = fmaxf(lmx[0][Rl], lmx[1][Rl]);
        part += mx + __logf(lsm[0][Rl] + lsm[1][Rl]);
      }
  }
#pragma unroll
  for (int mk = 1; mk < 64; mk <<= 1) part += __shfl_xor(part, mk, 64);
  if (lane == 0) bred[wid] = part;
  __syncthreads();
  if (tid == 0) atomicAdd(out, bred[0] + bred[1] + bred[2] + bred[3]);
}

extern "C" void kernel_launch(void* const* d_in, const int* in_sizes, int n_in,
                              void* d_out, int out_size, void* d_ws, size_t ws_size,
                              hipStream_t stream) {
  const float* e = (const float*)d_in[0];
  const float* wp = (const float*)d_in[1];
  const float* bp = (const float*)d_in[2];
  float* out = (float*)d_out;
  char* ws = (char*)d_ws;
  uint4* EbfA = (uint4*)ws;                              // 16 MB
  uint4* Cbf = (uint4*)(ws + (size_t)16 * 1024 * 1024);  // 1 MB
  float* SQ = (float*)(ws + (size_t)17 * 1024 * 1024);   // 128 KB

  k_prep<<<B * N, 256, 0, stream>>>(e, EbfA, Cbf, SQ, out);
  k_gemm<<<B * 64, 256, 0, stream>>>(EbfA, Cbf, SQ, wp, bp, out);
}